// Round 2
// baseline (198.568 us; speedup 1.0000x reference)
//
#include <hip/hip_runtime.h>
#include <hip/hip_bf16.h>
#include <stdint.h>

typedef unsigned short u16;
typedef unsigned int u32;
typedef __bf16 bf16x8 __attribute__((ext_vector_type(8)));
typedef _Float16 f16x8 __attribute__((ext_vector_type(8)));
typedef float f32x4 __attribute__((ext_vector_type(4)));
typedef float f32x16 __attribute__((ext_vector_type(16)));
typedef unsigned short u16x4 __attribute__((ext_vector_type(4)));
typedef unsigned int u32x4 __attribute__((ext_vector_type(4)));

#define SEQ     1024
#define DIM     768
#define NH      12
#define QKV_LD  2304
#define LOG2E   1.4426950408889634f
#define C1      0.18033688f   /* 0.125 * log2(e) */

__device__ __forceinline__ float bf2f(u16 u) {
    union { unsigned v; float f; } x; x.v = ((unsigned)u) << 16; return x.f;
}
__device__ __forceinline__ u16 f2bf(float f) {
    union { float f; unsigned v; } x; x.f = f;
    unsigned r = (x.v + 0x7FFFu + ((x.v >> 16) & 1u)) >> 16;
    return (u16)r;
}
__device__ __forceinline__ void store_out(u16* p, float v)  { *p = f2bf(v); }
__device__ __forceinline__ void store_out(float* p, float v){ *p = v; }

// async global->LDS, 16B per lane. HW semantics: LDS dest = wave base + lane*16.
__device__ __forceinline__ void async16(void* lds, const void* g) {
    __builtin_amdgcn_global_load_lds(
        (const __attribute__((address_space(1))) unsigned*)(uintptr_t)g,
        (__attribute__((address_space(3))) unsigned*)(unsigned)(uintptr_t)lds,
        16, 0, 0);
}

// ---------------- fp32 -> bf16 convert (x) ----------------
__global__ __launch_bounds__(256) void cvt_k(const float* __restrict__ in,
                                             u16* __restrict__ out) {
    int i = (blockIdx.x * 256 + threadIdx.x) * 4;
    float4 v = *(const float4*)(in + i);
    u16x4 o = { f2bf(v.x), f2bf(v.y), f2bf(v.z), f2bf(v.w) };
    *(u16x4*)(out + i) = o;
}

// ---------------- transpose + convert (fp32 weights -> bf16 B^T) ----------------
__global__ __launch_bounds__(256) void transpose_k(const float* __restrict__ in,
                                                   u16* __restrict__ out,
                                                   int R, int C) {
    __shared__ __align__(16) float t[32][33];
    int c0 = blockIdx.x * 32, r0 = blockIdx.y * 32;
    int tx = threadIdx.x & 31, ty = threadIdx.x >> 5;
#pragma unroll
    for (int i = 0; i < 32; i += 8)
        t[ty + i][tx] = in[(size_t)(r0 + ty + i) * C + c0 + tx];
    __syncthreads();
#pragma unroll
    for (int i = 0; i < 32; i += 8)
        out[(size_t)(c0 + ty + i) * R + r0 + tx] = f2bf(t[tx][ty + i]);
}

// -------- V transpose: ws_qkv V-slice (bf16) -> vT[b][h][dh][seq] (f16) --------
__global__ __launch_bounds__(256) void vt_k(const u16* __restrict__ qkv,
                                            _Float16* __restrict__ vT) {
    __shared__ __align__(16) u16 t[32][33];
    int bh = blockIdx.z;
    int b = bh / 12, h = bh % 12;
    int key0 = blockIdx.x * 32, dh0 = blockIdx.y * 32;
    int tx = threadIdx.x & 31, ty = threadIdx.x >> 5;
#pragma unroll
    for (int i = 0; i < 32; i += 8)
        t[ty + i][tx] = qkv[(size_t)(b * SEQ + key0 + ty + i) * QKV_LD +
                            1536 + h * 64 + dh0 + tx];
    __syncthreads();
#pragma unroll
    for (int i = 0; i < 32; i += 8)
        vT[(size_t)(bh * 64 + dh0 + ty + i) * SEQ + key0 + tx] =
            (_Float16)bf2f(t[tx][ty + i]);
}

// ------- GEMM: C[M,N] = A[M,K]*Bt[N,K]^T (+fp32 bias), bf16, BK=64 ------------
template <int HAS_BIAS, typename OUT_T>
__global__ __launch_bounds__(256) void gemm_bt(const u16* __restrict__ A,
                                               const u16* __restrict__ Bt,
                                               const float* __restrict__ bias,
                                               OUT_T* __restrict__ C,
                                               int M, int N, int K) {
    __shared__ __align__(16) u16 sA[128 * 64];
    __shared__ __align__(16) u16 sB[128 * 64];
    const int tid = threadIdx.x;
    const int lane = tid & 63;
    const int quad = lane >> 4, l16 = lane & 15;
    const int wave = tid >> 6;
    const int m0 = blockIdx.x * 128, n0 = blockIdx.y * 128;
    const int wm = (wave >> 1) * 64, wn = (wave & 1) * 64;

    const int co0 = (quad ^ (l16 & 7)) * 8;
    f32x4 acc[4][4] = {};

    for (int k0 = 0; k0 < K; k0 += 64) {
        __syncthreads();
#pragma unroll
        for (int rep = 0; rep < 4; ++rep) {
            int i = rep * 256 + tid;
            int row = i >> 3;
            int c = (i & 7) ^ (row & 7);
            async16(&sA[i * 8], A + (size_t)(m0 + row) * K + k0 + c * 8);
            async16(&sB[i * 8], Bt + (size_t)(n0 + row) * K + k0 + c * 8);
        }
        __syncthreads();

#pragma unroll
        for (int ks = 0; ks < 2; ++ks) {
            const int co = co0 ^ (ks * 32);
            bf16x8 af[4], bfr[4];
#pragma unroll
            for (int mi = 0; mi < 4; ++mi)
                af[mi] = *(const bf16x8*)&sA[(wm + mi * 16 + l16) * 64 + co];
#pragma unroll
            for (int nj = 0; nj < 4; ++nj)
                bfr[nj] = *(const bf16x8*)&sB[(wn + nj * 16 + l16) * 64 + co];
#pragma unroll
            for (int mi = 0; mi < 4; ++mi)
#pragma unroll
                for (int nj = 0; nj < 4; ++nj)
                    acc[mi][nj] = __builtin_amdgcn_mfma_f32_16x16x32_bf16(
                        af[mi], bfr[nj], acc[mi][nj], 0, 0, 0);
        }
    }

#pragma unroll
    for (int mi = 0; mi < 4; ++mi) {
#pragma unroll
        for (int nj = 0; nj < 4; ++nj) {
            int col = n0 + wn + nj * 16 + l16;
            float bv = HAS_BIAS ? bias[col] : 0.0f;
#pragma unroll
            for (int r = 0; r < 4; ++r) {
                int row = m0 + wm + mi * 16 + quad * 4 + r;
                store_out(&C[(size_t)row * N + col], acc[mi][nj][r] + bv);
            }
        }
    }
}

// ---------------- fused attention v8: 32x32 MFMAs, in-register P ----------------
// QK^T via mfma_f32_32x32x16_bf16 producing S^T (row=key=(reg&3)+8*(reg>>2)+4hi,
// col=q=lane&31). exp2 in f32, pack to f16 via cvt_pkrtz, then ONE
// __builtin_amdgcn_permlane32_swap per u32-pair assembles the B-operand frags
// (k = hi*8+j) of mfma_f32_32x32x16_f16 — P never touches LDS.
//   swap(first=wlo[2c] /keys m+16c+4hi/, second=wlo[2c+1] /keys m+16c+8+4hi/):
//   new first  = [own lo-keys | partner-lo's hi-keys]  -> W0 (k=hi*8+{0,1})
//   new second = [partner-hi's lo-keys | own hi-keys]  -> W2 (k=hi*8+{4,5})
// (v7 bug: inline asm reversed the halves AND bypassed LLVM's permlane hazard
// mitigation -> undefined reg reads -> NaN. Builtin fixes both.)
// PV: O^T[dh][q] += V^T-frag x P-frag (8 MFMA); osum via ones-MFMA (4).
// 20 MFMA/tile/wave vs 48 with 16x16 shapes (40 of which were half-rate K=16).
// LDS layouts & staging identical to v6; 40KB -> 3 blocks/CU (grid-limited).
__global__ __launch_bounds__(256, 3) void attn_k(const u16* __restrict__ qkv,
                                                 const _Float16* __restrict__ vT,
                                                 const float* __restrict__ bias_table,
                                                 u16* __restrict__ out) {
    __shared__ __align__(16) u16 sK[2][64 * 64];       // [key][dh], chunk-swizzled
    __shared__ __align__(16) _Float16 sV[2][64 * 64];  // [dh][key], chunk-swizzled
    __shared__ __align__(16) float sLut[2048];         // fp32 log2e*bias LUT

    const int tid = threadIdx.x;
    const int wave = tid >> 6, lane = tid & 63;
    const int l31 = lane & 31, hi = lane >> 5;
    const int bh = blockIdx.x;
    const int b = bh / NH, h = bh % NH;
    const int q0 = blockIdx.y * 128, wq = wave * 32;

    // bias LUT: lut[z] = log2e * bias[(z<=1023)?1023-z:z], z = 1023 + (i_q - j_key)
    for (int i = tid; i < 2047; i += 256)
        sLut[i] = LOG2E * bias_table[h * 2047 + (i <= 1023 ? 1023 - i : i)];

    // Q fragments: B-operand of 32x32x16_bf16 (col=q=l31, k = ks*16 + hi*8 + j)
    bf16x8 qf[4];
#pragma unroll
    for (int ks = 0; ks < 4; ++ks)
        qf[ks] = *(const bf16x8*)(qkv +
            (size_t)(b * SEQ + q0 + wq + l31) * QKV_LD + h * 64 + ks * 16 + hi * 8);

    // staging addresses (identical to v6)
    const u16* kgp[2];
    const _Float16* vgp[2];
    int lds_i[2];
#pragma unroll
    for (int rep = 0; rep < 2; ++rep) {
        int i = rep * 256 + wave * 64 + lane;
        int row = i >> 3;
        int c = (i & 7) ^ (row & 7);
        kgp[rep] = qkv + (size_t)(b * SEQ + row) * QKV_LD + 768 + h * 64 + c * 8;
        vgp[rep] = vT + (size_t)(bh * 64 + row) * SEQ + c * 8;
        lds_i[rep] = i * 8;
    }

    const int ib0 = 1023 + q0 + wq + l31;
    const int hi4 = hi * 4;

    // prologue: stage tile 0 into buffer 0
#pragma unroll
    for (int rep = 0; rep < 2; ++rep) {
        async16(&sK[0][lds_i[rep]], kgp[rep]);
        async16(&sV[0][lds_i[rep]], vgp[rep]);
        kgp[rep] += (size_t)64 * QKV_LD;
        vgp[rep] += 64;
    }
    __syncthreads();   // drains async, publishes LUT

    f32x16 o[2] = {};    // O^T: row dh = dt*32 + (reg&3)+8*(reg>>2)+4*hi, col q = l31
    f32x16 osum = {};    // all rows identical = sum_key P[key][q]
    const u32x4 onebits = { 0x3C003C00u, 0x3C003C00u, 0x3C003C00u, 0x3C003C00u };
    const f16x8 ones = __builtin_bit_cast(f16x8, onebits);

    for (int kt = 0; kt < SEQ / 64; ++kt) {
        const int cur = kt & 1;
        if (kt + 1 < SEQ / 64) {
            const int nxt = cur ^ 1;
#pragma unroll
            for (int rep = 0; rep < 2; ++rep) {
                async16(&sK[nxt][lds_i[rep]], kgp[rep]);
                async16(&sV[nxt][lds_i[rep]], vgp[rep]);
                kgp[rep] += (size_t)64 * QKV_LD;
                vgp[rep] += 64;
            }
        }
        const u16* sKc = sK[cur];
        const _Float16* sVc = sV[cur];

        // ---- S^T = K*Q^T (2 key-tiles) -> exp2 -> pack -> permlane swap ----
        f16x8 pfrag[4];   // B-frags for PV, kg = key group of 16
#pragma unroll
        for (int t = 0; t < 2; ++t) {
            const u16* kr = sKc + (t * 32 + l31) * 64;
            f32x16 s = {};
#pragma unroll
            for (int ks = 0; ks < 4; ++ks) {
                int slot = (2 * ks + hi) ^ (l31 & 7);
                bf16x8 af = *(const bf16x8*)(kr + slot * 8);
                s = __builtin_amdgcn_mfma_f32_32x32x16_bf16(af, qf[ks], s, 0, 0, 0);
            }
            // key = kt*64 + t*32 + m + 8g + 4hi ; z = ib0 - key
            const int ibt = ib0 - kt * 64 - t * 32 - hi4;
            u32 wlo[4], whi[4];
#pragma unroll
            for (int g = 0; g < 4; ++g) {
                const float* bw = &sLut[ibt - 8 * g];
                float p0 = __builtin_amdgcn_exp2f(s[4 * g + 0] * C1 + bw[0]);
                float p1 = __builtin_amdgcn_exp2f(s[4 * g + 1] * C1 + bw[-1]);
                float p2 = __builtin_amdgcn_exp2f(s[4 * g + 2] * C1 + bw[-2]);
                float p3 = __builtin_amdgcn_exp2f(s[4 * g + 3] * C1 + bw[-3]);
                wlo[g] = __builtin_bit_cast(u32, __builtin_amdgcn_cvt_pkrtz(p0, p1));
                whi[g] = __builtin_bit_cast(u32, __builtin_amdgcn_cvt_pkrtz(p2, p3));
            }
            // frag kg=2t+c: W0/W1 = keys 16kg+hi*8+{0..3}, W2/W3 = +4.
            // swap(wlo[2c], wlo[2c+1]): r[0]=W0, r[1]=W2 (see header comment).
#pragma unroll
            for (int c = 0; c < 2; ++c) {
                auto rlo = __builtin_amdgcn_permlane32_swap(
                    wlo[2 * c], wlo[2 * c + 1], false, false);
                auto rhi = __builtin_amdgcn_permlane32_swap(
                    whi[2 * c], whi[2 * c + 1], false, false);
                u32x4 f = { rlo[0], rhi[0], rlo[1], rhi[1] };   // W0,W1,W2,W3
                pfrag[t * 2 + c] = __builtin_bit_cast(f16x8, f);
            }
        }

        // ---- osum += ones x P ; O^T += V^T-frag x P-frag ----
#pragma unroll
        for (int kg = 0; kg < 4; ++kg)
            osum = __builtin_amdgcn_mfma_f32_32x32x16_f16(ones, pfrag[kg], osum, 0, 0, 0);
#pragma unroll
        for (int dt = 0; dt < 2; ++dt) {
            const _Float16* vr = sVc + (dt * 32 + l31) * 64;
#pragma unroll
            for (int kg = 0; kg < 4; ++kg) {
                int slot = (2 * kg + hi) ^ (l31 & 7);
                f16x8 vf = *(const f16x8*)(vr + slot * 8);
                o[dt] = __builtin_amdgcn_mfma_f32_32x32x16_f16(vf, pfrag[kg], o[dt], 0, 0, 0);
            }
        }
        __syncthreads();   // all waves done with buf[cur]; prefetch landed
    }

    // epilogue: lane q = q0+wq+l31; dh = dt*32 + 8g + 4hi + m
    float inv = __builtin_amdgcn_rcpf(osum[0]);
    size_t rowbase = (size_t)(b * SEQ + q0 + wq + l31) * DIM + h * 64 + hi4;
#pragma unroll
    for (int dt = 0; dt < 2; ++dt) {
#pragma unroll
        for (int g = 0; g < 4; ++g) {
            u16x4 pk = { f2bf(o[dt][4 * g + 0] * inv), f2bf(o[dt][4 * g + 1] * inv),
                         f2bf(o[dt][4 * g + 2] * inv), f2bf(o[dt][4 * g + 3] * inv) };
            *(u16x4*)&out[rowbase + dt * 32 + 8 * g] = pk;
        }
    }
}

extern "C" void kernel_launch(void* const* d_in, const int* in_sizes, int n_in,
                              void* d_out, int out_size, void* d_ws, size_t ws_size,
                              hipStream_t stream) {
    const float* x          = (const float*)d_in[0];  // (8,1024,768) fp32
    const float* w_qkv      = (const float*)d_in[1];  // (768,2304) fp32
    const float* bias_table = (const float*)d_in[2];  // (12,2047) fp32
    const float* w_out      = (const float*)d_in[3];  // (768,768) fp32
    const float* b_out      = (const float*)d_in[4];  // (768,) fp32
    float* out = (float*)d_out;                       // (8,1024,768) fp32

    char* ws = (char*)d_ws;
    u16* ws_qkv        = (u16*)(ws);                   // 37,748,736 B
    u16* ws_attn       = (u16*)(ws + 37748736);        // 12,582,912 B
    u16* ws_xb         = (u16*)(ws + 50331648);        // 12,582,912 B
    u16* ws_wqkvT      = (u16*)(ws + 62914560);        //  3,538,944 B
    u16* ws_woutT      = (u16*)(ws + 66453504);        //  1,179,648 B
    _Float16* ws_vT    = (_Float16*)(ws + 67633152);   // 12,582,912 B (tot 80.2MB)

    cvt_k<<<8 * 1024 * 768 / 1024, 256, 0, stream>>>(x, ws_xb);
    transpose_k<<<dim3(2304 / 32, 768 / 32), 256, 0, stream>>>(w_qkv, ws_wqkvT, 768, 2304);
    transpose_k<<<dim3(768 / 32, 768 / 32), 256, 0, stream>>>(w_out, ws_woutT, 768, 768);

    // qkv = x @ w_qkv : M=8192, N=2304, K=768
    gemm_bt<0, u16><<<dim3(8192 / 128, 2304 / 128), 256, 0, stream>>>(
        ws_xb, ws_wqkvT, nullptr, ws_qkv, 8192, 2304, 768);

    vt_k<<<dim3(SEQ / 32, 2, 8 * NH), 256, 0, stream>>>(ws_qkv, ws_vT);

    attn_k<<<dim3(8 * NH, SEQ / 128, 1), 256, 0, stream>>>(ws_qkv, ws_vT, bias_table, ws_attn);

    // out = attn @ w_out + b_out : M=8192, N=768, K=768
    gemm_bt<1, float><<<dim3(8192 / 128, 768 / 128), 256, 0, stream>>>(
        ws_attn, ws_woutT, b_out, out, 8192, 768, 768);
}

// Round 4
// 198.421 us; speedup vs baseline: 1.0007x; 1.0007x over previous
//
#include <hip/hip_runtime.h>
#include <hip/hip_bf16.h>
#include <stdint.h>

typedef unsigned short u16;
typedef unsigned int u32;
typedef __bf16 bf16x8 __attribute__((ext_vector_type(8)));
typedef _Float16 f16x8 __attribute__((ext_vector_type(8)));
typedef float f32x4 __attribute__((ext_vector_type(4)));
typedef float f32x16 __attribute__((ext_vector_type(16)));
typedef unsigned short u16x4 __attribute__((ext_vector_type(4)));
typedef unsigned int u32x4 __attribute__((ext_vector_type(4)));

#define SEQ     1024
#define DIM     768
#define NH      12
#define QKV_LD  2304
#define LOG2E   1.4426950408889634f
#define C1      0.18033688f   /* 0.125 * log2(e) */

__device__ __forceinline__ float bf2f(u16 u) {
    union { unsigned v; float f; } x; x.v = ((unsigned)u) << 16; return x.f;
}
__device__ __forceinline__ u16 f2bf(float f) {
    union { float f; unsigned v; } x; x.f = f;
    unsigned r = (x.v + 0x7FFFu + ((x.v >> 16) & 1u)) >> 16;
    return (u16)r;
}
__device__ __forceinline__ void store_out(u16* p, float v)  { *p = f2bf(v); }
__device__ __forceinline__ void store_out(float* p, float v){ *p = v; }

// async global->LDS, 16B per lane. HW semantics: LDS dest = wave base + lane*16.
__device__ __forceinline__ void async16(void* lds, const void* g) {
    __builtin_amdgcn_global_load_lds(
        (const __attribute__((address_space(1))) unsigned*)(uintptr_t)g,
        (__attribute__((address_space(3))) unsigned*)(unsigned)(uintptr_t)lds,
        16, 0, 0);
}

// ---------------- fp32 -> bf16 convert (x) ----------------
__global__ __launch_bounds__(256) void cvt_k(const float* __restrict__ in,
                                             u16* __restrict__ out) {
    int i = (blockIdx.x * 256 + threadIdx.x) * 4;
    float4 v = *(const float4*)(in + i);
    u16x4 o = { f2bf(v.x), f2bf(v.y), f2bf(v.z), f2bf(v.w) };
    *(u16x4*)(out + i) = o;
}

// ---------------- transpose + convert (fp32 weights -> bf16 B^T) ----------------
__global__ __launch_bounds__(256) void transpose_k(const float* __restrict__ in,
                                                   u16* __restrict__ out,
                                                   int R, int C) {
    __shared__ __align__(16) float t[32][33];
    int c0 = blockIdx.x * 32, r0 = blockIdx.y * 32;
    int tx = threadIdx.x & 31, ty = threadIdx.x >> 5;
#pragma unroll
    for (int i = 0; i < 32; i += 8)
        t[ty + i][tx] = in[(size_t)(r0 + ty + i) * C + c0 + tx];
    __syncthreads();
#pragma unroll
    for (int i = 0; i < 32; i += 8)
        out[(size_t)(c0 + ty + i) * R + r0 + tx] = f2bf(t[tx][ty + i]);
}

// -------- V transpose: ws_qkv V-slice (bf16) -> vT[b][h][dh][seq] (f16) --------
__global__ __launch_bounds__(256) void vt_k(const u16* __restrict__ qkv,
                                            _Float16* __restrict__ vT) {
    __shared__ __align__(16) u16 t[32][33];
    int bh = blockIdx.z;
    int b = bh / 12, h = bh % 12;
    int key0 = blockIdx.x * 32, dh0 = blockIdx.y * 32;
    int tx = threadIdx.x & 31, ty = threadIdx.x >> 5;
#pragma unroll
    for (int i = 0; i < 32; i += 8)
        t[ty + i][tx] = qkv[(size_t)(b * SEQ + key0 + ty + i) * QKV_LD +
                            1536 + h * 64 + dh0 + tx];
    __syncthreads();
#pragma unroll
    for (int i = 0; i < 32; i += 8)
        vT[(size_t)(bh * 64 + dh0 + ty + i) * SEQ + key0 + tx] =
            (_Float16)bf2f(t[tx][ty + i]);
}

// ------- GEMM: C[M,N] = A[M,K]*Bt[N,K]^T (+fp32 bias), bf16, BK=64 ------------
template <int HAS_BIAS, typename OUT_T>
__global__ __launch_bounds__(256) void gemm_bt(const u16* __restrict__ A,
                                               const u16* __restrict__ Bt,
                                               const float* __restrict__ bias,
                                               OUT_T* __restrict__ C,
                                               int M, int N, int K) {
    __shared__ __align__(16) u16 sA[128 * 64];
    __shared__ __align__(16) u16 sB[128 * 64];
    const int tid = threadIdx.x;
    const int lane = tid & 63;
    const int quad = lane >> 4, l16 = lane & 15;
    const int wave = tid >> 6;
    const int m0 = blockIdx.x * 128, n0 = blockIdx.y * 128;
    const int wm = (wave >> 1) * 64, wn = (wave & 1) * 64;

    const int co0 = (quad ^ (l16 & 7)) * 8;
    f32x4 acc[4][4] = {};

    for (int k0 = 0; k0 < K; k0 += 64) {
        __syncthreads();
#pragma unroll
        for (int rep = 0; rep < 4; ++rep) {
            int i = rep * 256 + tid;
            int row = i >> 3;
            int c = (i & 7) ^ (row & 7);
            async16(&sA[i * 8], A + (size_t)(m0 + row) * K + k0 + c * 8);
            async16(&sB[i * 8], Bt + (size_t)(n0 + row) * K + k0 + c * 8);
        }
        __syncthreads();

#pragma unroll
        for (int ks = 0; ks < 2; ++ks) {
            const int co = co0 ^ (ks * 32);
            bf16x8 af[4], bfr[4];
#pragma unroll
            for (int mi = 0; mi < 4; ++mi)
                af[mi] = *(const bf16x8*)&sA[(wm + mi * 16 + l16) * 64 + co];
#pragma unroll
            for (int nj = 0; nj < 4; ++nj)
                bfr[nj] = *(const bf16x8*)&sB[(wn + nj * 16 + l16) * 64 + co];
#pragma unroll
            for (int mi = 0; mi < 4; ++mi)
#pragma unroll
                for (int nj = 0; nj < 4; ++nj)
                    acc[mi][nj] = __builtin_amdgcn_mfma_f32_16x16x32_bf16(
                        af[mi], bfr[nj], acc[mi][nj], 0, 0, 0);
        }
    }

#pragma unroll
    for (int mi = 0; mi < 4; ++mi) {
#pragma unroll
        for (int nj = 0; nj < 4; ++nj) {
            int col = n0 + wn + nj * 16 + l16;
            float bv = HAS_BIAS ? bias[col] : 0.0f;
#pragma unroll
            for (int r = 0; r < 4; ++r) {
                int row = m0 + wm + mi * 16 + quad * 4 + r;
                store_out(&C[(size_t)row * N + col], acc[mi][nj][r] + bv);
            }
        }
    }
}

// -------- fused attention v9: cross-tile software pipeline (PV(t-1) || QK(t)) ----
// v8 was latency-bound (MfmaUtil 28, VALUBusy 33: serial QK->exp->PV chain,
// 3 waves/SIMD can't cover). v9 keeps V-frags + P-frags of tile kt in REGISTERS
// and executes PV(kt-1) inside the same barrier region as QK(kt): 20 MFMAs in
// 5 independent 4-deep chains + ds_reads for the scheduler to interleave.
// Single vf/pf register sets: WAR order (PV reads -> loads/pack overwrite)
// matches program order. V(kt) is reg-resident before segment kt+1's prefetch
// overwrites buf[kt&1]; __syncthreads' full drain covers in-flight ds_reads.
// s_setprio(1) wraps the MFMA cluster (T5). ~160 VGPR, launch_bounds(256,3).
__global__ __launch_bounds__(256, 3) void attn_k(const u16* __restrict__ qkv,
                                                 const _Float16* __restrict__ vT,
                                                 const float* __restrict__ bias_table,
                                                 u16* __restrict__ out) {
    __shared__ __align__(16) u16 sK[2][64 * 64];       // [key][dh], chunk-swizzled
    __shared__ __align__(16) _Float16 sV[2][64 * 64];  // [dh][key], chunk-swizzled
    __shared__ __align__(16) float sLut[2048];         // fp32 log2e*bias LUT

    const int tid = threadIdx.x;
    const int wave = tid >> 6, lane = tid & 63;
    const int l31 = lane & 31, hi = lane >> 5;
    const int bh = blockIdx.x;
    const int b = bh / NH, h = bh % NH;
    const int q0 = blockIdx.y * 128, wq = wave * 32;

    // bias LUT: lut[z] = log2e * bias[(z<=1023)?1023-z:z], z = 1023 + (i_q - j_key)
    for (int i = tid; i < 2047; i += 256)
        sLut[i] = LOG2E * bias_table[h * 2047 + (i <= 1023 ? 1023 - i : i)];

    // Q fragments: B-operand of 32x32x16_bf16 (col=q=l31, k = ks*16 + hi*8 + j)
    bf16x8 qf[4];
#pragma unroll
    for (int ks = 0; ks < 4; ++ks)
        qf[ks] = *(const bf16x8*)(qkv +
            (size_t)(b * SEQ + q0 + wq + l31) * QKV_LD + h * 64 + ks * 16 + hi * 8);

    // staging addresses
    const u16* kgp[2];
    const _Float16* vgp[2];
    int lds_i[2];
#pragma unroll
    for (int rep = 0; rep < 2; ++rep) {
        int i = rep * 256 + wave * 64 + lane;
        int row = i >> 3;
        int c = (i & 7) ^ (row & 7);
        kgp[rep] = qkv + (size_t)(b * SEQ + row) * QKV_LD + 768 + h * 64 + c * 8;
        vgp[rep] = vT + (size_t)(bh * 64 + row) * SEQ + c * 8;
        lds_i[rep] = i * 8;
    }

    const int ib0 = 1023 + q0 + wq + l31;
    const int hi4 = hi * 4;
    const int l7 = l31 & 7;

    // prologue: stage tile 0 into buffer 0
#pragma unroll
    for (int rep = 0; rep < 2; ++rep) {
        async16(&sK[0][lds_i[rep]], kgp[rep]);
        async16(&sV[0][lds_i[rep]], vgp[rep]);
        kgp[rep] += (size_t)64 * QKV_LD;
        vgp[rep] += 64;
    }
    __syncthreads();   // drains async, publishes LUT

    f32x16 o[2] = {};    // O^T: row dh = dt*32 + (reg&3)+8*(reg>>2)+4*hi, col q = l31
    f32x16 osum = {};    // all rows identical = sum_key P[key][q]
    const u32x4 onebits = { 0x3C003C00u, 0x3C003C00u, 0x3C003C00u, 0x3C003C00u };
    const f16x8 ones = __builtin_bit_cast(f16x8, onebits);

    f16x8 pf[4];         // P-frags of tile kt (B-operand, kg = key group of 16)
    f16x8 vf[8];         // V-frags of tile kt: vf[dt*4+kg]

    // segment helpers (macros keep register indexing static)
#define QK_TILE(sKc, kt, sAcc)                                                 \
    _Pragma("unroll")                                                          \
    for (int t = 0; t < 2; ++t) {                                              \
        const u16* kr = (sKc) + (t * 32 + l31) * 64;                           \
        f32x16 s = {};                                                         \
        _Pragma("unroll")                                                      \
        for (int ks = 0; ks < 4; ++ks) {                                       \
            int slot = (2 * ks + hi) ^ l7;                                     \
            bf16x8 af = *(const bf16x8*)(kr + slot * 8);                       \
            s = __builtin_amdgcn_mfma_f32_32x32x16_bf16(af, qf[ks], s, 0, 0, 0); \
        }                                                                      \
        sAcc[t] = s;                                                           \
    }

#define PV_PREV()                                                              \
    _Pragma("unroll")                                                          \
    for (int kg = 0; kg < 4; ++kg)                                             \
        osum = __builtin_amdgcn_mfma_f32_32x32x16_f16(ones, pf[kg], osum, 0, 0, 0); \
    _Pragma("unroll")                                                          \
    for (int dt = 0; dt < 2; ++dt)                                             \
        _Pragma("unroll")                                                      \
        for (int kg = 0; kg < 4; ++kg)                                         \
            o[dt] = __builtin_amdgcn_mfma_f32_32x32x16_f16(                    \
                vf[dt * 4 + kg], pf[kg], o[dt], 0, 0, 0);

#define LOAD_V(sVc)                                                            \
    _Pragma("unroll")                                                          \
    for (int dt = 0; dt < 2; ++dt) {                                           \
        const _Float16* vr = (sVc) + (dt * 32 + l31) * 64;                     \
        _Pragma("unroll")                                                      \
        for (int kg = 0; kg < 4; ++kg) {                                       \
            int slot = (2 * kg + hi) ^ l7;                                     \
            vf[dt * 4 + kg] = *(const f16x8*)(vr + slot * 8);                  \
        }                                                                      \
    }

#define EXP_PACK(kt, sAcc)                                                     \
    _Pragma("unroll")                                                          \
    for (int t = 0; t < 2; ++t) {                                              \
        const int ibt = ib0 - (kt) * 64 - t * 32 - hi4;                        \
        u32 wlo[4], whi[4];                                                    \
        _Pragma("unroll")                                                      \
        for (int g = 0; g < 4; ++g) {                                          \
            const float* bw = &sLut[ibt - 8 * g];                              \
            float p0 = __builtin_amdgcn_exp2f(sAcc[t][4 * g + 0] * C1 + bw[0]);  \
            float p1 = __builtin_amdgcn_exp2f(sAcc[t][4 * g + 1] * C1 + bw[-1]); \
            float p2 = __builtin_amdgcn_exp2f(sAcc[t][4 * g + 2] * C1 + bw[-2]); \
            float p3 = __builtin_amdgcn_exp2f(sAcc[t][4 * g + 3] * C1 + bw[-3]); \
            wlo[g] = __builtin_bit_cast(u32, __builtin_amdgcn_cvt_pkrtz(p0, p1)); \
            whi[g] = __builtin_bit_cast(u32, __builtin_amdgcn_cvt_pkrtz(p2, p3)); \
        }                                                                      \
        _Pragma("unroll")                                                      \
        for (int c = 0; c < 2; ++c) {                                          \
            auto rlo = __builtin_amdgcn_permlane32_swap(                       \
                wlo[2 * c], wlo[2 * c + 1], false, false);                     \
            auto rhi = __builtin_amdgcn_permlane32_swap(                       \
                whi[2 * c], whi[2 * c + 1], false, false);                     \
            u32x4 fw = { rlo[0], rhi[0], rlo[1], rhi[1] };                     \
            pf[t * 2 + c] = __builtin_bit_cast(f16x8, fw);                     \
        }                                                                      \
    }

#define PREFETCH(nxt)                                                          \
    _Pragma("unroll")                                                          \
    for (int rep = 0; rep < 2; ++rep) {                                        \
        async16(&sK[nxt][lds_i[rep]], kgp[rep]);                               \
        async16(&sV[nxt][lds_i[rep]], vgp[rep]);                               \
        kgp[rep] += (size_t)64 * QKV_LD;                                       \
        vgp[rep] += 64;                                                        \
    }

    { // ---- segment kt = 0: no PV yet ----
        PREFETCH(1)
        f32x16 sAcc[2];
        QK_TILE(sK[0], 0, sAcc)
        LOAD_V(sV[0])
        EXP_PACK(0, sAcc)
        __syncthreads();
    }

    for (int kt = 1; kt < SEQ / 64; ++kt) {
        const int cur = kt & 1;
        if (kt + 1 < SEQ / 64) { PREFETCH(cur ^ 1) }
        const u16* sKc = sK[cur];
        const _Float16* sVc = sV[cur];

        f32x16 sAcc[2];
        __builtin_amdgcn_s_setprio(1);
        QK_TILE(sKc, kt, sAcc)     // 8 MFMA (2 indep chains) for tile kt
        PV_PREV()                  // 12 MFMA (3 indep chains) for tile kt-1
        __builtin_amdgcn_s_setprio(0);
        LOAD_V(sVc)                // V(kt) -> regs (consumed next segment)
        EXP_PACK(kt, sAcc)         // P(kt) -> pf
        if (kt + 1 < SEQ / 64) __syncthreads();
    }

    // final PV for tile 15 (registers only)
    PV_PREV()

#undef QK_TILE
#undef PV_PREV
#undef LOAD_V
#undef EXP_PACK
#undef PREFETCH

    // epilogue: lane q = q0+wq+l31; dh = dt*32 + 8g + 4hi + m
    float inv = __builtin_amdgcn_rcpf(osum[0]);
    size_t rowbase = (size_t)(b * SEQ + q0 + wq + l31) * DIM + h * 64 + hi4;
#pragma unroll
    for (int dt = 0; dt < 2; ++dt) {
#pragma unroll
        for (int g = 0; g < 4; ++g) {
            u16x4 pk = { f2bf(o[dt][4 * g + 0] * inv), f2bf(o[dt][4 * g + 1] * inv),
                         f2bf(o[dt][4 * g + 2] * inv), f2bf(o[dt][4 * g + 3] * inv) };
            *(u16x4*)&out[rowbase + dt * 32 + 8 * g] = pk;
        }
    }
}

extern "C" void kernel_launch(void* const* d_in, const int* in_sizes, int n_in,
                              void* d_out, int out_size, void* d_ws, size_t ws_size,
                              hipStream_t stream) {
    const float* x          = (const float*)d_in[0];  // (8,1024,768) fp32
    const float* w_qkv      = (const float*)d_in[1];  // (768,2304) fp32
    const float* bias_table = (const float*)d_in[2];  // (12,2047) fp32
    const float* w_out      = (const float*)d_in[3];  // (768,768) fp32
    const float* b_out      = (const float*)d_in[4];  // (768,) fp32
    float* out = (float*)d_out;                       // (8,1024,768) fp32

    char* ws = (char*)d_ws;
    u16* ws_qkv        = (u16*)(ws);                   // 37,748,736 B
    u16* ws_attn       = (u16*)(ws + 37748736);        // 12,582,912 B
    u16* ws_xb         = (u16*)(ws + 50331648);        // 12,582,912 B
    u16* ws_wqkvT      = (u16*)(ws + 62914560);        //  3,538,944 B
    u16* ws_woutT      = (u16*)(ws + 66453504);        //  1,179,648 B
    _Float16* ws_vT    = (_Float16*)(ws + 67633152);   // 12,582,912 B (tot 80.2MB)

    cvt_k<<<8 * 1024 * 768 / 1024, 256, 0, stream>>>(x, ws_xb);
    transpose_k<<<dim3(2304 / 32, 768 / 32), 256, 0, stream>>>(w_qkv, ws_wqkvT, 768, 2304);
    transpose_k<<<dim3(768 / 32, 768 / 32), 256, 0, stream>>>(w_out, ws_woutT, 768, 768);

    // qkv = x @ w_qkv : M=8192, N=2304, K=768
    gemm_bt<0, u16><<<dim3(8192 / 128, 2304 / 128), 256, 0, stream>>>(
        ws_xb, ws_wqkvT, nullptr, ws_qkv, 8192, 2304, 768);

    vt_k<<<dim3(SEQ / 32, 2, 8 * NH), 256, 0, stream>>>(ws_qkv, ws_vT);

    attn_k<<<dim3(8 * NH, SEQ / 128, 1), 256, 0, stream>>>(ws_qkv, ws_vT, bias_table, ws_attn);

    // out = attn @ w_out + b_out : M=8192, N=768, K=768
    gemm_bt<1, float><<<dim3(8192 / 128, 768 / 128), 256, 0, stream>>>(
        ws_attn, ws_woutT, b_out, out, 8192, 768, 768);
}